// Round 5
// baseline (245.365 us; speedup 1.0000x reference)
//
#include <hip/hip_runtime.h>

namespace {
constexpr int H = 512;
constexpr int W = 512;
constexpr int NC = 96;                 // 32 images * 3 channels (independent planes)
constexpr int RSTRIP = 32;             // output rows per wave
constexpr int SPP = H / RSTRIP;        // 16 row-strips per plane
constexpr int NQ = 4;                  // four 128-col quarters per row
constexpr int NSTRIPS = NC * NQ * SPP; // 6144 waves = 24/CU, single round at 8 waves/SIMD
constexpr int WPB = 4;                 // waves per block
constexpr int NTHR = WPB * 64;         // 256
constexpr int NBLK = NSTRIPS / WPB;    // 1536 blocks
constexpr float INV_K2 = 1.0f / 49.0f;
constexpr float INV_TOTAL = 1.0f / (32.0f * 3.0f * 512.0f * 512.0f);
}

// One row step, 2 columns per lane. P8/P4 compile-time ring phases -> static indices.
template <int P8, int P4, bool EMIT>
__device__ __forceinline__ void proc_row(
    const float2* __restrict__ pred2, const float2* __restrict__ targ2,
    const float4* __restrict__ pred4, const float4* __restrict__ targ4,
    int y, int base2, int base4, int col2, int q32, int lane,
    bool haloL, bool haloR,
    float (&hr)[8][2], float (&dr)[4][2], float (&vs)[2], float& acc)
{
    float2 d = make_float2(0.f, 0.f);
    float4 g = make_float4(0.f, 0.f, 0.f, 0.f);   // cross-quarter halo (lanes 0,1,62,63)
    if ((unsigned)y < (unsigned)H) {
        const int i2 = base2 + y * (W / 2) + col2;
        const float2 a = pred2[i2];
        const float2 b = targ2[i2];
        d.x = a.x - b.x;
        d.y = a.y - b.y;
        if (haloL | haloR) {
            const int i4 = base4 + y * (W / 4) + q32 + (haloL ? -1 : 32);
            const float4 ga = pred4[i4];
            const float4 gb = targ4[i4];
            g.x = ga.x - gb.x; g.y = ga.y - gb.y;
            g.z = ga.z - gb.z; g.w = ga.w - gb.w;
        }
    }

    // halo: window is [c-3, c+3] for own cols c0=2*lane, c0+1
    float u2  = __shfl_up(d.y, 2);     // col c0-3
    float u1x = __shfl_up(d.x, 1);     // col c0-2
    float u1y = __shfl_up(d.y, 1);     // col c0-1
    float n1x = __shfl_down(d.x, 1);   // col c0+2
    float n1y = __shfl_down(d.y, 1);   // col c0+3
    float n2  = __shfl_down(d.x, 2);   // col c0+4
    if (lane == 0)       { u2 = g.y; u1x = g.z; u1y = g.w; }
    else if (lane == 1)  { u2 = g.w; }
    else if (lane == 62) { n2 = g.x; }
    else if (lane == 63) { n1x = g.x; n1y = g.y; n2 = g.z; }

    const float h0 = ((u2 + u1x) + (u1y + d.x)) + ((d.y + n1x) + n1y);
    const float h1 = h0 - u2 + n2;

    constexpr int S  = P8 & 7;
    constexpr int So = (P8 + 1) & 7;   // h from 7 rows ago
    constexpr int Q  = P4 & 3;
    constexpr int Qo = (P4 + 1) & 3;   // d from 3 rows ago

    vs[0] += h0 - hr[So][0]; hr[S][0] = h0;
    vs[1] += h1 - hr[So][1]; hr[S][1] = h1;

    if (EMIT) {
        acc += fabsf(dr[Qo][0] - vs[0] * INV_K2)
             + fabsf(dr[Qo][1] - vs[1] * INV_K2);
    }

    dr[Q][0] = d.x;
    dr[Q][1] = d.y;
}

__global__ __launch_bounds__(NTHR, 8) void lcl_partial(
    const float2* __restrict__ pred2, const float2* __restrict__ targ2,
    float* __restrict__ partials)
{
    const float4* pred4 = (const float4*)pred2;
    const float4* targ4 = (const float4*)targ2;

    const int tid   = threadIdx.x;
    const int lane  = tid & 63;
    const int wv    = tid >> 6;
    const int strip = blockIdx.x * WPB + wv;
    const int plane = strip >> 6;                  // 64 strips per plane
    const int rem   = strip & 63;
    const int quarter = rem >> 4;
    const int y0    = (rem & 15) * RSTRIP;
    const int base2 = plane * (H * (W / 2));
    const int base4 = plane * (H * (W / 4));
    const int col2  = quarter * 64 + lane;         // float2 index within row
    const int q32   = quarter * 32;                // float4 index of quarter start
    const bool haloL = (lane <= 1)  && (quarter > 0);
    const bool haloR = (lane >= 62) && (quarter < 3);

    float hr[8][2], dr[4][2], vs[2];
#pragma unroll
    for (int s = 0; s < 8; ++s) { hr[s][0] = 0.f; hr[s][1] = 0.f; }
#pragma unroll
    for (int s = 0; s < 4; ++s) { dr[s][0] = 0.f; dr[s][1] = 0.f; }
    vs[0] = 0.f; vs[1] = 0.f;
    float acc = 0.f;

    // prologue: rows y0-3 .. y0+2 (phases 0..5), no output yet
    proc_row<0, 0, false>(pred2, targ2, pred4, targ4, y0 - 3, base2, base4, col2, q32, lane, haloL, haloR, hr, dr, vs, acc);
    proc_row<1, 1, false>(pred2, targ2, pred4, targ4, y0 - 2, base2, base4, col2, q32, lane, haloL, haloR, hr, dr, vs, acc);
    proc_row<2, 2, false>(pred2, targ2, pred4, targ4, y0 - 1, base2, base4, col2, q32, lane, haloL, haloR, hr, dr, vs, acc);
    proc_row<3, 3, false>(pred2, targ2, pred4, targ4, y0    , base2, base4, col2, q32, lane, haloL, haloR, hr, dr, vs, acc);
    proc_row<4, 0, false>(pred2, targ2, pred4, targ4, y0 + 1, base2, base4, col2, q32, lane, haloL, haloR, hr, dr, vs, acc);
    proc_row<5, 1, false>(pred2, targ2, pred4, targ4, y0 + 2, base2, base4, col2, q32, lane, haloL, haloR, hr, dr, vs, acc);

    // steady state: 4 runtime iterations x 8-row unrolled body (phases repeat mod 8)
#pragma unroll 1
    for (int b = 0; b < 4; ++b) {
        const int yb = y0 + 3 + b * 8;
        proc_row<6, 2, true>(pred2, targ2, pred4, targ4, yb    , base2, base4, col2, q32, lane, haloL, haloR, hr, dr, vs, acc);
        proc_row<7, 3, true>(pred2, targ2, pred4, targ4, yb + 1, base2, base4, col2, q32, lane, haloL, haloR, hr, dr, vs, acc);
        proc_row<0, 0, true>(pred2, targ2, pred4, targ4, yb + 2, base2, base4, col2, q32, lane, haloL, haloR, hr, dr, vs, acc);
        proc_row<1, 1, true>(pred2, targ2, pred4, targ4, yb + 3, base2, base4, col2, q32, lane, haloL, haloR, hr, dr, vs, acc);
        proc_row<2, 2, true>(pred2, targ2, pred4, targ4, yb + 4, base2, base4, col2, q32, lane, haloL, haloR, hr, dr, vs, acc);
        proc_row<3, 3, true>(pred2, targ2, pred4, targ4, yb + 5, base2, base4, col2, q32, lane, haloL, haloR, hr, dr, vs, acc);
        proc_row<4, 0, true>(pred2, targ2, pred4, targ4, yb + 6, base2, base4, col2, q32, lane, haloL, haloR, hr, dr, vs, acc);
        proc_row<5, 1, true>(pred2, targ2, pred4, targ4, yb + 7, base2, base4, col2, q32, lane, haloL, haloR, hr, dr, vs, acc);
    }

    // wave reduce, one partial per strip
#pragma unroll
    for (int off = 32; off > 0; off >>= 1)
        acc += __shfl_down(acc, off, 64);
    if (lane == 0) partials[strip] = acc;
}

__global__ __launch_bounds__(256) void lcl_reduce(const float* __restrict__ partials,
                                                  float* __restrict__ out)
{
    __shared__ float wred[4];
    const int tid = threadIdx.x;
    float s = 0.0f;
    for (int i = tid; i < NSTRIPS; i += 256) s += partials[i];
#pragma unroll
    for (int off = 32; off > 0; off >>= 1)
        s += __shfl_down(s, off, 64);
    if ((tid & 63) == 0) wred[tid >> 6] = s;
    __syncthreads();
    if (tid == 0) out[0] = ((wred[0] + wred[1]) + (wred[2] + wred[3])) * INV_TOTAL;
}

extern "C" void kernel_launch(void* const* d_in, const int* in_sizes, int n_in,
                              void* d_out, int out_size, void* d_ws, size_t ws_size,
                              hipStream_t stream) {
    const float2* pred2 = (const float2*)d_in[0];
    const float2* targ2 = (const float2*)d_in[1];
    float* out      = (float*)d_out;
    float* partials = (float*)d_ws;   // NSTRIPS floats = 24 KB

    lcl_partial<<<NBLK, NTHR, 0, stream>>>(pred2, targ2, partials);
    lcl_reduce<<<1, 256, 0, stream>>>(partials, out);
}

// Round 6
// 61.270 us; speedup vs baseline: 4.0046x; 4.0046x over previous
//
#include <hip/hip_runtime.h>

namespace {
constexpr int H = 512;
constexpr int W = 512;
constexpr int NC = 96;                 // 32 images * 3 channels (independent planes)
constexpr int RSTRIP = 16;             // output rows per wave
constexpr int SPP = H / RSTRIP;        // 32 row-strips per plane
constexpr int NHALF = 2;               // two 256-col halves per row
constexpr int NSTRIPS = NC * NHALF * SPP;  // 6144 waves
constexpr int WPB = 4;                 // waves per block
constexpr int NTHR = WPB * 64;         // 256
constexpr int NBLK = NSTRIPS / WPB;    // 1536 blocks
constexpr float INV_K2 = 1.0f / 49.0f;
constexpr float INV_TOTAL = 1.0f / (32.0f * 3.0f * 512.0f * 512.0f);
}

// One row step. P8/P4 are compile-time ring phases -> all array indices static.
template <int P8, int P4, bool EMIT>
__device__ __forceinline__ void proc_row(
    const float4* __restrict__ pred4, const float4* __restrict__ targ4,
    int y, int base4, int col4, int lane, bool edgeL, bool edgeR,
    float (&hr)[8][4], float (&dr)[4][4], float (&vs)[4], float& acc)
{
    float4 d  = make_float4(0.f, 0.f, 0.f, 0.f);
    float4 dx = make_float4(0.f, 0.f, 0.f, 0.f);
    if ((unsigned)y < (unsigned)H) {
        const int idx = base4 + y * (W / 4) + col4;
        const float4 a = pred4[idx];
        const float4 b = targ4[idx];
        d.x = a.x - b.x; d.y = a.y - b.y; d.z = a.z - b.z; d.w = a.w - b.w;
        if (edgeL | edgeR) {                       // 2 lanes of 64, wave-edge halo
            const int e = idx + (edgeR ? 1 : -1);
            const float4 ea = pred4[e];
            const float4 eb = targ4[e];
            dx.x = ea.x - eb.x; dx.y = ea.y - eb.y;
            dx.z = ea.z - eb.z; dx.w = ea.w - eb.w;
        }
    }

    // column halo from neighbor lanes (4 cols/lane)
    float l1 = __shfl_up(d.y, 1);
    float l2 = __shfl_up(d.z, 1);
    float l3 = __shfl_up(d.w, 1);
    float r1 = __shfl_down(d.x, 1);
    float r2 = __shfl_down(d.y, 1);
    float r3 = __shfl_down(d.z, 1);
    if (lane == 0)  { l1 = dx.y; l2 = dx.z; l3 = dx.w; }
    if (lane == 63) { r1 = dx.x; r2 = dx.y; r3 = dx.z; }

    // horizontal 7-sums, incremental
    const float h0 = ((l1 + l2) + (l3 + d.x)) + ((d.y + d.z) + d.w);
    const float h1 = h0 - l1 + r1;
    const float h2 = h1 - l2 + r2;
    const float h3 = h2 - l3 + r3;

    constexpr int S  = P8 & 7;
    constexpr int So = (P8 + 1) & 7;   // h from 7 rows ago
    constexpr int Q  = P4 & 3;
    constexpr int Qo = (P4 + 1) & 3;   // d from 3 rows ago

    vs[0] += h0 - hr[So][0]; hr[S][0] = h0;
    vs[1] += h1 - hr[So][1]; hr[S][1] = h1;
    vs[2] += h2 - hr[So][2]; hr[S][2] = h2;
    vs[3] += h3 - hr[So][3]; hr[S][3] = h3;

    if (EMIT) {
        acc += fabsf(dr[Qo][0] - vs[0] * INV_K2)
             + fabsf(dr[Qo][1] - vs[1] * INV_K2)
             + fabsf(dr[Qo][2] - vs[2] * INV_K2)
             + fabsf(dr[Qo][3] - vs[3] * INV_K2);
    }

    dr[Q][0] = d.x; dr[Q][1] = d.y; dr[Q][2] = d.z; dr[Q][3] = d.w;
}

__global__ __launch_bounds__(NTHR, 3) void lcl_partial(
    const float4* __restrict__ pred4, const float4* __restrict__ targ4,
    float* __restrict__ partials)
{
    const int tid   = threadIdx.x;
    const int lane  = tid & 63;
    const int wv    = tid >> 6;
    const int strip = blockIdx.x * WPB + wv;
    const int plane = strip >> 6;                    // 64 strips per plane
    const int rem   = strip & 63;
    const int half  = rem >> 5;
    const int y0    = (rem & 31) * RSTRIP;
    const int base4 = plane * (H * (W / 4));
    const int col4  = half * 64 + lane;              // float4 index in row (0..127)
    const bool edgeL = (lane == 0)  && (half == 1);
    const bool edgeR = (lane == 63) && (half == 0);

    float hr[8][4], dr[4][4], vs[4];
#pragma unroll
    for (int s = 0; s < 8; ++s) { hr[s][0]=0.f; hr[s][1]=0.f; hr[s][2]=0.f; hr[s][3]=0.f; }
#pragma unroll
    for (int s = 0; s < 4; ++s) { dr[s][0]=0.f; dr[s][1]=0.f; dr[s][2]=0.f; dr[s][3]=0.f; }
    vs[0]=0.f; vs[1]=0.f; vs[2]=0.f; vs[3]=0.f;
    float acc = 0.f;

    // prologue: rows y0-3 .. y0+2 (phases 0..5), no output yet
    proc_row<0, 0, false>(pred4, targ4, y0 - 3, base4, col4, lane, edgeL, edgeR, hr, dr, vs, acc);
    proc_row<1, 1, false>(pred4, targ4, y0 - 2, base4, col4, lane, edgeL, edgeR, hr, dr, vs, acc);
    proc_row<2, 2, false>(pred4, targ4, y0 - 1, base4, col4, lane, edgeL, edgeR, hr, dr, vs, acc);
    proc_row<3, 3, false>(pred4, targ4, y0    , base4, col4, lane, edgeL, edgeR, hr, dr, vs, acc);
    proc_row<4, 0, false>(pred4, targ4, y0 + 1, base4, col4, lane, edgeL, edgeR, hr, dr, vs, acc);
    proc_row<5, 1, false>(pred4, targ4, y0 + 2, base4, col4, lane, edgeL, edgeR, hr, dr, vs, acc);

    // steady state: 2 runtime iterations x 8-row unrolled body (phases repeat mod 8)
#pragma unroll 1
    for (int b = 0; b < 2; ++b) {
        const int yb = y0 + 3 + b * 8;
        proc_row<6, 2, true>(pred4, targ4, yb    , base4, col4, lane, edgeL, edgeR, hr, dr, vs, acc);
        proc_row<7, 3, true>(pred4, targ4, yb + 1, base4, col4, lane, edgeL, edgeR, hr, dr, vs, acc);
        proc_row<0, 0, true>(pred4, targ4, yb + 2, base4, col4, lane, edgeL, edgeR, hr, dr, vs, acc);
        proc_row<1, 1, true>(pred4, targ4, yb + 3, base4, col4, lane, edgeL, edgeR, hr, dr, vs, acc);
        proc_row<2, 2, true>(pred4, targ4, yb + 4, base4, col4, lane, edgeL, edgeR, hr, dr, vs, acc);
        proc_row<3, 3, true>(pred4, targ4, yb + 5, base4, col4, lane, edgeL, edgeR, hr, dr, vs, acc);
        proc_row<4, 0, true>(pred4, targ4, yb + 6, base4, col4, lane, edgeL, edgeR, hr, dr, vs, acc);
        proc_row<5, 1, true>(pred4, targ4, yb + 7, base4, col4, lane, edgeL, edgeR, hr, dr, vs, acc);
    }

    // wave reduce, one partial per strip
#pragma unroll
    for (int off = 32; off > 0; off >>= 1)
        acc += __shfl_down(acc, off, 64);
    if (lane == 0) partials[strip] = acc;
}

__global__ __launch_bounds__(256) void lcl_reduce(const float* __restrict__ partials,
                                                  float* __restrict__ out)
{
    __shared__ float wred[4];
    const int tid = threadIdx.x;
    float s = 0.0f;
    for (int i = tid; i < NSTRIPS; i += 256) s += partials[i];
#pragma unroll
    for (int off = 32; off > 0; off >>= 1)
        s += __shfl_down(s, off, 64);
    if ((tid & 63) == 0) wred[tid >> 6] = s;
    __syncthreads();
    if (tid == 0) out[0] = ((wred[0] + wred[1]) + (wred[2] + wred[3])) * INV_TOTAL;
}

extern "C" void kernel_launch(void* const* d_in, const int* in_sizes, int n_in,
                              void* d_out, int out_size, void* d_ws, size_t ws_size,
                              hipStream_t stream) {
    const float4* pred4 = (const float4*)d_in[0];
    const float4* targ4 = (const float4*)d_in[1];
    float* out      = (float*)d_out;
    float* partials = (float*)d_ws;   // NSTRIPS floats = 24 KB

    lcl_partial<<<NBLK, NTHR, 0, stream>>>(pred4, targ4, partials);
    lcl_reduce<<<1, 256, 0, stream>>>(partials, out);
}